// Round 11
// baseline (444.472 us; speedup 1.0000x reference)
//
#include <hip/hip_runtime.h>
#include <hip/hip_bf16.h>

#define BB 16
#define SS 2048
#define DD 64
#define NTB 16   // 2048 k / 128 per tile

typedef __attribute__((ext_vector_type(8)))  unsigned short ushort8;
typedef __attribute__((ext_vector_type(8)))  __bf16 bf16x8;
typedef __attribute__((ext_vector_type(16))) float f32x16;

static __device__ __forceinline__ unsigned short f2bf(float x) {
    return __builtin_bit_cast(unsigned short, __float2bfloat16(x));
}
static __device__ __forceinline__ unsigned pk2(float a, float b) {
    return (unsigned)f2bf(a) | ((unsigned)f2bf(b) << 16);
}
union F4 { float4 v; float a[4]; };

// bf16 MFMA attention, 32x32x16 tiles. Composition of the two proven wins:
//  - Phase A (r10-proven): bitpack this block's CONTIGUOUS 256 KB mask region
//    (sequential row-major stream) into an 8 KB LDS bit-tile.
//  - Phase B (r6-proven): q-tile 32, k-tile 128, 4 waves own k-chunks, mask
//    stage deleted (1 ds_read_b32 + bit test). 4 blocks/CU (LDS exactly
//    40 KB) so block-local barriers overlap across blocks (m114).
// Core: S^T = K*Q^T; P via shfl_xor(32) exchange (r5-proven); O^T = V^T*P^T.
// Mask = int32 words (proven r4+). No max-subtraction: logits bounded;
// masked -> p = 1.0f exactly (exp(1e-9)==1.0f). No reg prefetch across
// barriers (r9 spill lesson) -> VGPR well under the (256,4) cap of 128.
__global__ __launch_bounds__(256, 4)
void sdpa_mfma_kernel(const float* __restrict__ Q, const float* __restrict__ K,
                      const float* __restrict__ V, const unsigned int* __restrict__ M,
                      float* __restrict__ O) {
    // smem: Ks 16K (128k x 64d bf16) | Vs 16K (V^T 64d x 128k) | X 8K
    // X = Qs (pre-loop) then Bits ([kw 0..63][32 q-words, +kw rotation]).
    // Epilogue reuse: red = smem (24 KB), denx = smem+24576 (dead regions).
    __shared__ __align__(16) char smem[40960];
    char* Ks   = smem;
    char* Vs   = smem + 16384;
    char* Qs   = smem + 32768;
    char* Bits = smem + 32768;

    const int t    = threadIdx.x;
    const int lane = t & 63;
    const int l31  = lane & 31;
    const int half = lane >> 5;
    const int kh   = t >> 6;          // wave owns k-chunk 32*kh of each 128-tile
    const int b    = blockIdx.y;
    const int q0   = blockIdx.x * 32;

    const float* Kg = K + (size_t)b * SS * DD;
    const float* Vg = V + (size_t)b * SS * DD;
    const unsigned int* Mblk = M + (size_t)b * SS * SS + (size_t)q0 * SS;

    // ---- Phase A prefetch of row 0 (issued first for latency cover) ----
    const int kw  = t >> 2;           // k-window 0..63 (32 k each)
    const int bsh = 8 * (t & 3);
    uint4 c0 = *(const uint4*)(Mblk + 8 * t);
    uint4 c1 = *(const uint4*)(Mblk + 8 * t + 4);

    // ---- stage Q (pre-scaled by 1/temperature), swizzled bf16, 32 rows ----
    {
        const int sr = t >> 3, sc = t & 7;
        const float* src = Q + ((size_t)b * SS + q0 + sr) * DD + sc * 8;
        F4 f0, f1; f0.v = *(const float4*)src; f1.v = *(const float4*)(src + 4);
        ushort8 u;
        #pragma unroll
        for (int e = 0; e < 4; e++) {
            u[e]     = f2bf(f0.a[e] * 0.125f);
            u[e + 4] = f2bf(f1.a[e] * 0.125f);
        }
        *(ushort8*)(Qs + sr * 128 + ((sc ^ (sr & 7)) * 16)) = u;
    }
    __syncthreads();

    // ---- preload Q fragments (B operand); all 4 waves share the q-tile ----
    const int qrow = l31;
    bf16x8 bq[4];
    #pragma unroll
    for (int dc = 0; dc < 4; dc++)
        bq[dc] = __builtin_bit_cast(bf16x8, *(const ushort8*)(
            Qs + qrow * 128 + (((2 * dc + half) ^ (qrow & 7)) * 16)));
    __syncthreads();   // Qs dead -> region becomes Bits

    // ---- Phase A: bitpack 32 rows x 8 KB (contiguous 256 KB), ping-pong ----
    for (int s = 0; s < 32; ++s) {
        const int sn = (s + 1 < 32) ? s + 1 : 31;
        const uint4 n0 = *(const uint4*)(Mblk + (size_t)sn * SS + 8 * t);
        const uint4 n1 = *(const uint4*)(Mblk + (size_t)sn * SS + 8 * t + 4);
        unsigned byt = (unsigned)(c0.x != 0u)        | ((unsigned)(c0.y != 0u) << 1)
                     | ((unsigned)(c0.z != 0u) << 2) | ((unsigned)(c0.w != 0u) << 3)
                     | ((unsigned)(c1.x != 0u) << 4) | ((unsigned)(c1.y != 0u) << 5)
                     | ((unsigned)(c1.z != 0u) << 6) | ((unsigned)(c1.w != 0u) << 7);
        unsigned v = byt << bsh;
        v |= (unsigned)__shfl_xor((int)v, 1, 64);
        v |= (unsigned)__shfl_xor((int)v, 2, 64);
        if ((t & 3) == 0)
            *(unsigned*)(Bits + kw * 128 + (((s + kw) & 31) << 2)) = v;
        c0 = n0; c1 = n1;
    }
    __syncthreads();

    f32x16 On0, On1;           // O^T accumulators: d 0..31 / 32..63
    #pragma unroll
    for (int i = 0; i < 16; i++) { On0[i] = 0.f; On1[i] = 0.f; }
    float den_acc = 0.f;

    const int krow = 32 * kh + l31;
    const int d0v  = (t & 15) * 4;   // V staging: d columns
    const int kk4  = (t >> 4) * 4;   // V staging: k row quad base

    // ---- Phase B: r6-proven k128 loop, mask from LDS bits ----
    for (int kt = 0; kt < NTB; ++kt) {
        // ---- stage K tile 128x64: flat coalesced float4 pairs -> b128 ----
        #pragma unroll
        for (int j = 0; j < 4; j++) {
            const int idx = 2 * t + 512 * j;        // float4 index in tile
            const int row = idx >> 4;
            const int g   = (idx & 15) >> 1;        // 16B granule
            const float* src = Kg + (size_t)(kt * 128) * DD + (size_t)idx * 4;
            F4 fa, fb; fa.v = *(const float4*)src; fb.v = *(const float4*)(src + 4);
            ushort8 u;
            #pragma unroll
            for (int e = 0; e < 4; e++) { u[e] = f2bf(fa.a[e]); u[e + 4] = f2bf(fb.a[e]); }
            *(ushort8*)(Ks + row * 128 + ((g ^ (row & 7)) * 16)) = u;
        }
        // ---- stage V transposed: Vs[d][k], uint2 writes (r6-proven) ----
        #pragma unroll
        for (int it2 = 0; it2 < 2; it2++) {
            const int kk = kk4 + 64 * it2;
            const float* src = Vg + (size_t)(kt * 128 + kk) * DD + d0v;
            F4 r0, r1, r2, r3;
            r0.v = *(const float4*)(src);
            r1.v = *(const float4*)(src + DD);
            r2.v = *(const float4*)(src + 2 * DD);
            r3.v = *(const float4*)(src + 3 * DD);
            #pragma unroll
            for (int e = 0; e < 4; e++) {
                const int d = d0v + e;
                *(uint2*)(Vs + d * 256 + (((kk >> 3) ^ (d & 15)) * 16) + (kk & 7) * 2)
                    = make_uint2(pk2(r0.a[e], r1.a[e]), pk2(r2.a[e], r3.a[e]));
            }
        }
        __syncthreads();

        // ---- QK^T: S^T tile [32k x 32q] for this wave's k-chunk ----
        f32x16 S;
        #pragma unroll
        for (int i = 0; i < 16; i++) S[i] = 0.f;
        #pragma unroll
        for (int dc = 0; dc < 4; dc++) {
            bf16x8 ak = __builtin_bit_cast(bf16x8, *(const ushort8*)(
                Ks + krow * 128 + (((2 * dc + half) ^ (krow & 7)) * 16)));
            S = __builtin_amdgcn_mfma_f32_32x32x16_bf16(ak, bq[dc], S, 0, 0, 0);
        }

        // ---- mask bits + exp + denominator (C row = e + 8g + 4half) ----
        const int kwi = 4 * kt + kh;
        const unsigned bitw = *(const unsigned*)(Bits + kwi * 128 +
                                  (((l31 + kwi) & 31) << 2));
        float p[16];
        #pragma unroll
        for (int g = 0; g < 4; g++) {
            #pragma unroll
            for (int e = 0; e < 4; e++) {
                const float ev = __expf(S[4 * g + e]);
                const float pv = ((bitw >> (4 * half + 8 * g + e)) & 1u) ? 1.0f : ev;
                p[4 * g + e] = pv;
                den_acc += pv;
            }
        }

        // ---- P·V: B-operand frags via shfl_xor(32) (proven r5), 2 ksubs ----
        #pragma unroll
        for (int s2 = 0; s2 < 2; s2++) {
            const unsigned o0 = pk2(p[8 * s2 + 0], p[8 * s2 + 1]);
            const unsigned o1 = pk2(p[8 * s2 + 2], p[8 * s2 + 3]);
            const unsigned o2 = pk2(p[8 * s2 + 4], p[8 * s2 + 5]);
            const unsigned o3 = pk2(p[8 * s2 + 6], p[8 * s2 + 7]);
            const unsigned s0 = half ? o0 : o2;
            const unsigned s1 = half ? o1 : o3;
            const unsigned r0 = (unsigned)__shfl_xor((int)s0, 32, 64);
            const unsigned r1 = (unsigned)__shfl_xor((int)s1, 32, 64);
            uint4 bu;
            bu.x = half ? r0 : o0;
            bu.y = half ? r1 : o1;
            bu.z = half ? o2 : r0;
            bu.w = half ? o3 : r1;
            const bf16x8 bp = __builtin_bit_cast(bf16x8, bu);
            #pragma unroll
            for (int dc2 = 0; dc2 < 2; dc2++) {
                const int vrow = 32 * dc2 + l31;
                bf16x8 av = __builtin_bit_cast(bf16x8, *(const ushort8*)(
                    Vs + vrow * 256 + (((4 * kh + 2 * s2 + half) ^ (vrow & 15)) * 16)));
                if (dc2 == 0) On0 = __builtin_amdgcn_mfma_f32_32x32x16_bf16(av, bp, On0, 0, 0, 0);
                else          On1 = __builtin_amdgcn_mfma_f32_32x32x16_bf16(av, bp, On1, 0, 0, 0);
            }
        }
        __syncthreads();
    }

    // ---- epilogue: lane halves, then 4-way k-split reduction (r6-proven) ----
    const float den_tot = den_acc + __shfl_xor(den_acc, 32, 64);
    float* red  = (float*)smem;             // 24 KB (Ks + half Vs, dead)
    float* denx = (float*)(smem + 24576);   // in Vs, dead

    if (kh != 0) {
        #pragma unroll
        for (int dc = 0; dc < 2; dc++)
            #pragma unroll
            for (int g = 0; g < 4; g++) {
                const f32x16& Oc = dc ? On1 : On0;
                float4 st;
                st.x = Oc[4 * g + 0]; st.y = Oc[4 * g + 1];
                st.z = Oc[4 * g + 2]; st.w = Oc[4 * g + 3];
                *(float4*)((char*)red + (kh - 1) * 8192 + (dc * 4 + g) * 1024 + lane * 16) = st;
            }
        if (lane < 32) denx[kh * 32 + l31] = den_tot;
    }
    __syncthreads();
    if (kh == 0) {
        const float inv = 1.0f / (den_tot + denx[32 + l31] + denx[64 + l31] + denx[96 + l31]);
        float* Og = O + ((size_t)b * SS + q0 + qrow) * DD;
        #pragma unroll
        for (int dc = 0; dc < 2; dc++)
            #pragma unroll
            for (int g = 0; g < 4; g++) {
                const f32x16& Oc = dc ? On1 : On0;
                float4 st;
                st.x = Oc[4 * g + 0]; st.y = Oc[4 * g + 1];
                st.z = Oc[4 * g + 2]; st.w = Oc[4 * g + 3];
                #pragma unroll
                for (int w2 = 0; w2 < 3; w2++) {
                    const float4 pr = *(const float4*)((char*)red + w2 * 8192 +
                                                       (dc * 4 + g) * 1024 + lane * 16);
                    st.x += pr.x; st.y += pr.y; st.z += pr.z; st.w += pr.w;
                }
                st.x *= inv; st.y *= inv; st.z *= inv; st.w *= inv;
                // d = e + 8g + 4half + 32dc  (C-row formula)
                *(float4*)(Og + 32 * dc + 8 * g + 4 * half) = st;
            }
    }
}

extern "C" void kernel_launch(void* const* d_in, const int* in_sizes, int n_in,
                              void* d_out, int out_size, void* d_ws, size_t ws_size,
                              hipStream_t stream) {
    const float* q = (const float*)d_in[0];
    const float* k = (const float*)d_in[1];
    const float* v = (const float*)d_in[2];
    const unsigned int* m = (const unsigned int*)d_in[3];
    float* out = (float*)d_out;

    dim3 grid(SS / 32, BB);   // 64 x 16 = 1024 blocks -> 4 per CU
    sdpa_mfma_kernel<<<grid, 256, 0, stream>>>(q, k, v, m, out);
}